// Round 6
// baseline (214.886 us; speedup 1.0000x reference)
//
#include <hip/hip_runtime.h>

#define TC 128
#define KD 64
#define WLOG_MIN (-5.2983174f)   // ln(0.005)

typedef __attribute__((ext_vector_type(8))) short short8;
typedef __attribute__((ext_vector_type(4))) short short4_t;
typedef __attribute__((ext_vector_type(4))) float f32x4;

__device__ __forceinline__ unsigned short f2bf(float x) {
  union { float f; unsigned int u; } c; c.f = x;
  unsigned int u = c.u + 0x7fffu + ((c.u >> 16) & 1u);   // RNE
  return (unsigned short)(u >> 16);
}
__device__ __forceinline__ float bf2f(unsigned short x) {
  union { unsigned int u; float f; } c; c.u = ((unsigned int)x) << 16; return c.f;
}

// rd_s/ki_s swizzle: element (t,kd) at t*64 + (slot<<3 | kd&7),
// slot = (kd>>3) ^ (t&7) ^ ((t>>3)&7).  vT swizzle: slot = g ^ (row&7).
// sT (K2): slot = (kd>>3) ^ (vd&7) ^ ((vd>>3)&7).

// ---------------------------------------------------------------------------
// K1: per-(b,h,chunk). 54,272B LDS -> 3 blocks/CU. Two barriers.
// Staging remapped to float4: thread = (t-quarter tq, 4-kd-column group c16).
// ---------------------------------------------------------------------------
__global__ __launch_bounds__(256, 3)
void rwkv_intra_mfma(const float* __restrict__ rr, const float* __restrict__ kk_,
                     const float* __restrict__ vv, const float* __restrict__ ww,
                     const float* __restrict__ uu, float* __restrict__ out,
                     unsigned short* __restrict__ wkv_u16, float* __restrict__ wse_ws,
                     unsigned short* __restrict__ rw_u16, unsigned short* __restrict__ diag_u16,
                     int H, int N) {
  __shared__ alignas(16) unsigned short rd_s[TC * KD];
  __shared__ alignas(16) unsigned short ki_s[TC * KD];
  __shared__ alignas(16) unsigned short vT_s[KD * TC];
  __shared__ alignas(16) unsigned char su_raw[5120];   // union: segtot f32[4][64] | Ast u16[4][640]
  float* segtot = (float*)su_raw;
  unsigned short* Ast = (unsigned short*)su_raw;

  const int bid = blockIdx.x;
  const int n = bid % N, bh = bid / N, h = bh % H;
  const size_t base = ((size_t)bh * N + n) * (TC * KD);
  const float *rg = rr + base, *kg = kk_ + base, *vg = vv + base, *wg = ww + base;
  unsigned short* diagg = diag_u16 + (size_t)bid * TC;

  const int tid = threadIdx.x;
  const int wv = tid >> 6;          // wave id = t-segment of 32
  const int lane = tid & 63;
  const int tq = lane >> 4;         // t-quarter within segment (8 t's)
  const int c16 = lane & 15;        // 4-kd column group
  const int kd0 = c16 * 4;

  // ---- pass 1: w float4 loads + per-column cumsum + tq-prefix ----
  float4 wl4[8];
  float4 pre;
  {
    float4 loc = make_float4(0.f, 0.f, 0.f, 0.f);
    #pragma unroll
    for (int i = 0; i < 8; ++i) {
      const int t = wv * 32 + tq * 8 + i;
      float4 w4 = *(const float4*)&wg[t * KD + kd0];
      wl4[i] = make_float4(fmaxf(w4.x, WLOG_MIN), fmaxf(w4.y, WLOG_MIN),
                           fmaxf(w4.z, WLOG_MIN), fmaxf(w4.w, WLOG_MIN));
      loc.x += wl4[i].x; loc.y += wl4[i].y; loc.z += wl4[i].z; loc.w += wl4[i].w;
    }
    float4 p0, p1, p2;
    p0.x = __shfl(loc.x, c16, 64);      p0.y = __shfl(loc.y, c16, 64);
    p0.z = __shfl(loc.z, c16, 64);      p0.w = __shfl(loc.w, c16, 64);
    p1.x = __shfl(loc.x, 16 + c16, 64); p1.y = __shfl(loc.y, 16 + c16, 64);
    p1.z = __shfl(loc.z, 16 + c16, 64); p1.w = __shfl(loc.w, 16 + c16, 64);
    p2.x = __shfl(loc.x, 32 + c16, 64); p2.y = __shfl(loc.y, 32 + c16, 64);
    p2.z = __shfl(loc.z, 32 + c16, 64); p2.w = __shfl(loc.w, 32 + c16, 64);
    pre = make_float4(0.f, 0.f, 0.f, 0.f);
    if (tq >= 1) { pre.x += p0.x; pre.y += p0.y; pre.z += p0.z; pre.w += p0.w; }
    if (tq >= 2) { pre.x += p1.x; pre.y += p1.y; pre.z += p1.z; pre.w += p1.w; }
    if (tq >= 3) { pre.x += p2.x; pre.y += p2.y; pre.z += p2.z; pre.w += p2.w; }
    if (tq == 3) {
      float4 st4 = make_float4(pre.x + loc.x, pre.y + loc.y, pre.z + loc.z, pre.w + loc.w);
      *(float4*)&segtot[wv * 64 + kd0] = st4;
    }
  }
  __syncthreads();

  // lane-as-column view (lane = kd) for wsoff/wse (MFMA epilogue uses shuffle)
  float wsoff_own;
  {
    const float t0 = segtot[0 * 64 + lane], t1 = segtot[1 * 64 + lane];
    const float t2 = segtot[2 * 64 + lane], t3 = segtot[3 * 64 + lane];
    wsoff_own = __expf(t2 + t3);   // wsum - myoff
    if (wv == 0) wse_ws[((size_t)bh * N + n) * KD + lane] = __expf(t0 + t1 + t2 + t3);
  }
  // column-group view for staging
  float4 s0 = *(const float4*)&segtot[0 * 64 + kd0];
  float4 s1 = *(const float4*)&segtot[1 * 64 + kd0];
  float4 myoff4 = make_float4(s0.x + s1.x, s0.y + s1.y, s0.z + s1.z, s0.w + s1.w);
  float4 segofs4;
  {
    float4 s2 = *(const float4*)&segtot[2 * 64 + kd0];
    segofs4 = make_float4(0.f, 0.f, 0.f, 0.f);
    if (wv >= 1) { segofs4.x += s0.x; segofs4.y += s0.y; segofs4.z += s0.z; segofs4.w += s0.w; }
    if (wv >= 2) { segofs4.x += s1.x; segofs4.y += s1.y; segofs4.z += s1.z; segofs4.w += s1.w; }
    if (wv >= 3) { segofs4.x += s2.x; segofs4.y += s2.y; segofs4.z += s2.z; segofs4.w += s2.w; }
  }
  const float4 eoff4 = make_float4(__expf(myoff4.x), __expf(myoff4.y),
                                   __expf(myoff4.z), __expf(myoff4.w));

  // ---- pass 2: staging (float4 loads, b64 LDS writes) ----
  {
    float4 c4 = make_float4(segofs4.x + pre.x, segofs4.y + pre.y,
                            segofs4.z + pre.z, segofs4.w + pre.w);
    const float4 uk4 = *(const float4*)&uu[h * KD + kd0];
    unsigned short* rwg = rw_u16 + base;
    short8 vb8[4];
    float dpart[8];
    const int g = wv * 4 + tq;
    #pragma unroll
    for (int i = 0; i < 8; ++i) {
      const int t = wv * 32 + tq * 8 + i;
      float4 r4 = *(const float4*)&rg[t * KD + kd0];
      float4 k4 = *(const float4*)&kg[t * KD + kd0];
      float4 v4 = *(const float4*)&vg[t * KD + kd0];
      float4 e1 = make_float4(__expf(c4.x - myoff4.x), __expf(c4.y - myoff4.y),
                              __expf(c4.z - myoff4.z), __expf(c4.w - myoff4.w));
      const int slot = (c16 >> 1) ^ (i) ^ (g & 7);            // t&7 == i
      const int nat = t * KD + (slot << 3) + ((c16 & 1) << 2);
      short4_t rdp, rwp, kip;
      rdp[0] = (short)f2bf(r4.x * e1.x); rdp[1] = (short)f2bf(r4.y * e1.y);
      rdp[2] = (short)f2bf(r4.z * e1.z); rdp[3] = (short)f2bf(r4.w * e1.w);
      rwp[0] = (short)f2bf(r4.x * e1.x * eoff4.x); rwp[1] = (short)f2bf(r4.y * e1.y * eoff4.y);
      rwp[2] = (short)f2bf(r4.z * e1.z * eoff4.z); rwp[3] = (short)f2bf(r4.w * e1.w * eoff4.w);
      kip[0] = (short)f2bf(k4.x * __expf(myoff4.x - c4.x - wl4[i].x));
      kip[1] = (short)f2bf(k4.y * __expf(myoff4.y - c4.y - wl4[i].y));
      kip[2] = (short)f2bf(k4.z * __expf(myoff4.z - c4.z - wl4[i].z));
      kip[3] = (short)f2bf(k4.w * __expf(myoff4.w - c4.w - wl4[i].w));
      *(short4_t*)&rd_s[nat] = rdp;
      *(short4_t*)&ki_s[nat] = kip;
      *(short4_t*)&rwg[t * KD + kd0] = rwp;
      vb8[0][i] = (short)f2bf(v4.x); vb8[1][i] = (short)f2bf(v4.y);
      vb8[2][i] = (short)f2bf(v4.z); vb8[3][i] = (short)f2bf(v4.w);
      dpart[i] = r4.x * uk4.x * k4.x + r4.y * uk4.y * k4.y +
                 r4.z * uk4.z * k4.z + r4.w * uk4.w * k4.w;
      c4.x += wl4[i].x; c4.y += wl4[i].y; c4.z += wl4[i].z; c4.w += wl4[i].w;
    }
    #pragma unroll
    for (int j = 0; j < 4; ++j) {
      const int vd = kd0 + j;
      *(short8*)&vT_s[vd * TC + ((g ^ (vd & 7)) << 3)] = vb8[j];
    }
    #pragma unroll
    for (int o = 1; o < 16; o <<= 1)
      #pragma unroll
      for (int i = 0; i < 8; ++i) dpart[i] += __shfl_xor(dpart[i], o, 64);
    if (c16 == 0) {
      short8 dpk;
      #pragma unroll
      for (int i = 0; i < 8; ++i) dpk[i] = (short)f2bf(dpart[i]);
      *(short8*)&diagg[g * 8] = dpk;
    }
  }
  __syncthreads();

  const int quad = lane >> 4, l16 = lane & 15;

  // ---- wkv = (ki * w_inter)^T @ v -> bf16 ws (A-frags via scalar LDS reads) ----
  {
    f32x4 acc[4] = {{0,0,0,0},{0,0,0,0},{0,0,0,0},{0,0,0,0}};
    const int kdg = wv * 2 + (l16 >> 3), kd7 = l16 & 7;
    #pragma unroll
    for (int ks = 0; ks < 4; ++ks) {
      short8 a;
      #pragma unroll
      for (int j = 0; j < 8; ++j) {
        const int t = ks * 32 + quad * 8 + j;
        a[j] = (short)ki_s[t * KD + (((kdg ^ (t & 7) ^ ((t >> 3) & 7)) << 3) + kd7)];
      }
      #pragma unroll
      for (int nn = 0; nn < 4; ++nn) {
        const int vd = nn * 16 + l16;
        short8 b = *(const short8*)&vT_s[vd * TC + (((ks * 4 + quad) ^ (vd & 7)) << 3)];
        acc[nn] = __builtin_amdgcn_mfma_f32_16x16x32_bf16(a, b, acc[nn], 0, 0, 0);
      }
    }
    float wso[4];
    #pragma unroll
    for (int reg = 0; reg < 4; ++reg) wso[reg] = __shfl(wsoff_own, wv * 16 + quad * 4 + reg, 64);
    unsigned short* wkvg = wkv_u16 + ((size_t)bh * N + n) * (KD * KD);
    #pragma unroll
    for (int nn = 0; nn < 4; ++nn)
      #pragma unroll
      for (int reg = 0; reg < 4; ++reg)
        wkvg[(wv * 16 + quad * 4 + reg) * KD + nn * 16 + l16] = f2bf(acc[nn][reg] * wso[reg]);
  }

  // ---- fused A^T tiles + out = A@v (per-wave, no block sync) ----
  #pragma unroll
  for (int half = 0; half < 2; ++half) {
    const int ib = half ? (7 - wv) : wv;
    const int i0 = ib * 16;
    const int irow = i0 + l16;
    const int rsw = (irow & 7) ^ ((irow >> 3) & 7);
    short8 b0 = *(const short8*)&rd_s[irow * KD + ((quad ^ rsw) << 3)];
    short8 b1 = *(const short8*)&rd_s[irow * KD + (((4 + quad) ^ rsw) << 3)];
    const float diag_i = bf2f(diagg[irow]);
    f32x4 oacc[4] = {{0,0,0,0},{0,0,0,0},{0,0,0,0},{0,0,0,0}};
    const int npairs = (ib + 2) >> 1;
    unsigned short* astw = Ast + wv * 640;
    for (int jp = 0; jp < npairs; ++jp) {
      #pragma unroll
      for (int jj = 0; jj < 2; ++jj) {
        const int j = jp * 2 + jj;
        short4_t pk;
        if (j <= ib) {
          const int jrow = j * 16 + l16;
          const int jsw = (jrow & 7) ^ ((jrow >> 3) & 7);
          short8 a0 = *(const short8*)&ki_s[jrow * KD + ((quad ^ jsw) << 3)];
          short8 a1 = *(const short8*)&ki_s[jrow * KD + (((4 + quad) ^ jsw) << 3)];
          f32x4 at = {0, 0, 0, 0};
          at = __builtin_amdgcn_mfma_f32_16x16x32_bf16(a0, b0, at, 0, 0, 0);
          at = __builtin_amdgcn_mfma_f32_16x16x32_bf16(a1, b1, at, 0, 0, 0);
          #pragma unroll
          for (int reg = 0; reg < 4; ++reg) {
            const int je = j * 16 + quad * 4 + reg;
            float val = at[reg];
            if (j == ib) val = (je < irow) ? val : ((je == irow) ? diag_i : 0.f);
            pk[reg] = (short)f2bf(val);
          }
        } else {
          pk = (short4_t)0;  // guard half for even ib
        }
        *(short4_t*)&astw[l16 * 40 + jj * 16 + quad * 4] = pk;
      }
      short8 af = *(const short8*)&astw[l16 * 40 + quad * 8];
      #pragma unroll
      for (int nn = 0; nn < 4; ++nn) {
        const int vd = nn * 16 + l16;
        short8 bv = *(const short8*)&vT_s[vd * TC + (((jp * 4 + quad) ^ (vd & 7)) << 3)];
        oacc[nn] = __builtin_amdgcn_mfma_f32_16x16x32_bf16(af, bv, oacc[nn], 0, 0, 0);
      }
    }
    float* og = out + base;
    #pragma unroll
    for (int nn = 0; nn < 4; ++nn)
      #pragma unroll
      for (int reg = 0; reg < 4; ++reg)
        og[(i0 + quad * 4 + reg) * KD + nn * 16 + l16] = oacc[nn][reg];
  }
}

// ---------------------------------------------------------------------------
// K2: per-(b,h,chunk,vd-half) block (2048 blocks). Inline redundant scan
// (pipelined backward sweep over predecessor wkv chunks, L2-resident), LDS
// transpose of S, out += rw @ S (rw A-frags hoisted to kernel entry).
// 4KB LDS -> high occupancy.
// ---------------------------------------------------------------------------
__global__ __launch_bounds__(256)
void rwkv_state_inter(const unsigned short* __restrict__ wkv_u16,
                      const float* __restrict__ wse_ws,
                      const float* __restrict__ st_in,
                      const unsigned short* __restrict__ rw_u16,
                      float* __restrict__ out, float* __restrict__ final_out, int N) {
  __shared__ alignas(16) unsigned short sT[32 * KD];  // [vd_l][kd] swizzled
  const int bid = blockIdx.x;
  const int half = bid & 1;
  const int cn = bid >> 1;
  const int n = cn % N, bh = cn / N;
  const int tid = threadIdx.x;
  const size_t cbase = (size_t)bh * N;

  const int lane = tid & 63, wvv = tid >> 6, quad = lane >> 4, l16 = lane & 15;

  // Hoisted A-fragments (independent of the sweep): rw rows for this chunk.
  const unsigned short* rwg = rw_u16 + (cbase + n) * (TC * KD);
  short8 afr[4];
  #pragma unroll
  for (int half2 = 0; half2 < 2; ++half2) {
    const int trow = (wvv + half2 * 4) * 16 + l16;
    afr[half2 * 2 + 0] = *(const short8*)&rwg[trow * KD + quad * 8];
    afr[half2 * 2 + 1] = *(const short8*)&rwg[trow * KD + 32 + quad * 8];
  }

  // ---- pipelined backward sweep ----
  const int kd = tid >> 2;                    // 0..63
  const int vv = (tid & 3) * 8 + half * 32;   // 8 v-columns
  float S[8];
  #pragma unroll
  for (int j = 0; j < 8; ++j) S[j] = 0.f;
  float P = 1.f;
  {
    int m = n - 1;
    short8 a_nx = {0,0,0,0,0,0,0,0};
    float e_nx = 0.f;
    if (m >= 0) {
      a_nx = *(const short8*)&wkv_u16[(cbase + m) * (KD * KD) + kd * KD + vv];
      e_nx = wse_ws[(cbase + m) * KD + kd];
    }
    while (m >= 0) {
      short8 a = a_nx; float e = e_nx;
      if (m - 1 >= 0) {
        a_nx = *(const short8*)&wkv_u16[(cbase + m - 1) * (KD * KD) + kd * KD + vv];
        e_nx = wse_ws[(cbase + m - 1) * KD + kd];
      }
      #pragma unroll
      for (int j = 0; j < 8; ++j) S[j] += P * bf2f((unsigned short)a[j]);
      P *= e;
      --m;
    }
  }
  {
    const float* s0g = st_in + (size_t)bh * (KD * KD) + kd * KD + vv;
    float4 q0 = *(const float4*)&s0g[0];
    float4 q1 = *(const float4*)&s0g[4];
    S[0] += P * q0.x; S[1] += P * q0.y; S[2] += P * q0.z; S[3] += P * q0.w;
    S[4] += P * q1.x; S[5] += P * q1.y; S[6] += P * q1.z; S[7] += P * q1.w;
  }
  if (n == N - 1) {  // final state output
    const unsigned short* wk = wkv_u16 + (cbase + N - 1) * (KD * KD) + kd * KD + vv;
    short8 a = *(const short8*)wk;
    const float e = wse_ws[(cbase + N - 1) * KD + kd];
    float* fo = final_out + (size_t)bh * (KD * KD) + kd * KD + vv;
    #pragma unroll
    for (int j = 0; j < 8; ++j) fo[j] = S[j] * e + bf2f((unsigned short)a[j]);
  }
  // LDS transpose: sT[vd_l][kd], slot = (kd>>3) ^ (vd_l&7) ^ ((vd_l>>3)&7)
  #pragma unroll
  for (int j = 0; j < 8; ++j) {
    const int vd_l = (tid & 3) * 8 + j;
    const int rs = (vd_l & 7) ^ ((vd_l >> 3) & 7);
    sT[vd_l * KD + ((((kd >> 3) ^ rs) << 3) | (kd & 7))] = f2bf(S[j]);
  }
  __syncthreads();

  // ---- out += rw @ S ----
  float* og = out + (cbase + n) * (TC * KD);
  #pragma unroll
  for (int half2 = 0; half2 < 2; ++half2) {
    const int mt = wvv + half2 * 4;
    short8 a0 = afr[half2 * 2 + 0];
    short8 a1 = afr[half2 * 2 + 1];
    f32x4 acc[2] = {{0,0,0,0},{0,0,0,0}};
    #pragma unroll
    for (int nn = 0; nn < 2; ++nn) {
      const int vd_l = nn * 16 + l16;
      const int rs = (vd_l & 7) ^ ((vd_l >> 3) & 7);
      short8 b0 = *(const short8*)&sT[vd_l * KD + ((quad ^ rs) << 3)];
      short8 b1 = *(const short8*)&sT[vd_l * KD + (((4 + quad) ^ rs) << 3)];
      acc[nn] = __builtin_amdgcn_mfma_f32_16x16x32_bf16(a0, b0, acc[nn], 0, 0, 0);
      acc[nn] = __builtin_amdgcn_mfma_f32_16x16x32_bf16(a1, b1, acc[nn], 0, 0, 0);
    }
    #pragma unroll
    for (int nn = 0; nn < 2; ++nn)
      #pragma unroll
      for (int reg = 0; reg < 4; ++reg)
        og[(size_t)(mt * 16 + quad * 4 + reg) * KD + half * 32 + nn * 16 + l16] += acc[nn][reg];
  }
}

// ---------------------------------------------------------------------------
// Workspace (~25.7 MB): [wkv u16: BH*N*K*K][wse f32: BH*N*K]
//                       [rw u16: BH*T*K][diag u16: BH*N*TC]
// ---------------------------------------------------------------------------
extern "C" void kernel_launch(void* const* d_in, const int* in_sizes, int n_in,
                              void* d_out, int out_size, void* d_ws, size_t ws_size,
                              hipStream_t stream) {
  const float* r = (const float*)d_in[0];
  const float* k = (const float*)d_in[1];
  const float* v = (const float*)d_in[2];
  const float* w = (const float*)d_in[3];
  const float* u = (const float*)d_in[4];
  const float* st0 = (const float*)d_in[5];
  float* out = (float*)d_out;

  const int BH = in_sizes[5] / (KD * KD);  // 64
  const int H = in_sizes[4] / KD;          // 16
  const int T = in_sizes[0] / (BH * KD);   // 2048
  const int N = T / TC;                    // 16

  unsigned short* wkv_u16 = (unsigned short*)d_ws;
  float* wse_ws = (float*)(wkv_u16 + (size_t)BH * N * KD * KD);
  unsigned short* rw_u16 = (unsigned short*)(wse_ws + (size_t)BH * N * KD);
  unsigned short* diag_u16 = rw_u16 + (size_t)BH * T * KD;
  float* final_out = out + (size_t)in_sizes[0];

  rwkv_intra_mfma<<<BH * N, 256, 0, stream>>>(r, k, v, w, u, out, wkv_u16, wse_ws,
                                              rw_u16, diag_u16, H, N);
  rwkv_state_inter<<<BH * N * 2, 256, 0, stream>>>(wkv_u16, wse_ws, st0, rw_u16,
                                                   out, final_out, N);
}